// Round 1
// 108.514 us; speedup vs baseline: 1.0848x; 1.0848x over previous
//
#include <hip/hip_runtime.h>

typedef _Float16 f16;
typedef f16 f16x8 __attribute__((ext_vector_type(8)));
typedef f16 f16x4 __attribute__((ext_vector_type(4)));
typedef float f32x4 __attribute__((ext_vector_type(4)));

// ---- LDS tile strides/offsets (units: f16 elements), 16x8-pixel tile ----
// x0: 11 rows x 24 cols (gy in [ty*8-1,  ty*8+10)),  stride 28
// x1: 20 rows x 44 cols (gy in [ty*16-2, ty*16+18)), stride 48
// x2: 40 rows x 88 cols (gy in [ty*32-4, ty*32+36)), stride 92
#define S0 28
#define S1 48
#define S2 92
#define T0OFF 0
#define T1OFF (11 * S0)                 // 308
#define T2OFF (T1OFF + 20 * S1)         // 1268
#define TILEH (T2OFF + 40 * S2)         // 4948 f16 = 9896 B
#define LOG2E 1.4426950408889634f

// K' = 256 layout (8 ksteps of 32):
//  kp in [0,16)   : layer0, ki=kp>>2, kj=kp&3   ; real iff ki<3 && kj<3 -> orig = 3*ki+kj
//  kp in [16,64)  : layer1, kk=kp-16, ki=kk>>3, kj=kk&7 ; real iff kj<6 -> orig = 9+6*ki+kj
//  kp in [64,256) : layer2, kk=kp-64, ki=kk>>4, kj=kk&15; real iff kj<12 -> orig = 45+12*ki+kj
//
// Fragment-major storage: fragment f = (s*4 + t)*64 + lane holds the 8 f16
// W-elements (k = s*32 + quad*8 + j, n = t*16 + ln) -> every wave load is
// 64 lanes x 16 B CONTIGUOUS (1 KB).  This layout serves as the *A* operand
// now (operand-swapped MFMA): A[m=ln][k=quad*8+j] = W[k][chan=t*16+ln].
__global__ void prep_wt(const float* __restrict__ W, f16* __restrict__ Wt) {
  const int f = blockIdx.x * 256 + threadIdx.x;   // 0..2047
  const int s = f >> 8;
  const int t = (f >> 6) & 3;
  const int lane = f & 63;
  const int quad = lane >> 4, ln = lane & 15;
  const int n = t * 16 + ln;
  f16 vals[8];
  #pragma unroll
  for (int j = 0; j < 8; ++j) {
    int kp = s * 32 + quad * 8 + j;
    int orig = -1;
    if (kp < 16)      { int ki = kp >> 2, kj = kp & 3;                   if (ki < 3 && kj < 3) orig = 3*ki + kj; }
    else if (kp < 64) { int kk = kp - 16; int ki = kk >> 3, kj = kk & 7;  if (kj < 6)          orig = 9 + 6*ki + kj; }
    else              { int kk = kp - 64; int ki = kk >> 4, kj = kk & 15; if (kj < 12)         orig = 45 + 12*ki + kj; }
    vals[j] = (f16)((orig >= 0) ? W[orig * 64 + n] : 0.f);
  }
  *(f16x8*)(Wt + (size_t)f * 8) = *(const f16x8*)vals;
}

// Operand-swapped MFMA: D = W_frag * patch_frag, so D col = lane&15 = pixel-x,
// D row = 4*quad + r = channel-in-group.  chan = 16t + 4*quad + r
//   -> u0 = chan>>3 = 2t + (quad>>1), u1 = chan&7 = 4*(quad&1) + r
//   -> per (cc,t) store is one f32x4; wave covers two contiguous 512 B runs.
// Softmax over 64 channels of one pixel = 16 in-lane values + shfl_xor(16,32).
// No LDS scratch, no transpose barriers: one barrier in the whole kernel.
__global__ __launch_bounds__(256, 6) void fuse_kernel(
    const float* __restrict__ x0, const float* __restrict__ x1,
    const float* __restrict__ x2, const f16* __restrict__ Wt,
    float* __restrict__ out)
{
  __shared__ __align__(16) f16 tiles[TILEH];

  const int tid  = threadIdx.x;
  // bijective XCD swizzle: 2048 wgs = 8 XCDs x 256; XCD k owns images [8k, 8k+8)
  const int bid  = ((blockIdx.x & 7) << 8) | (blockIdx.x >> 3);
  const int nb   = bid >> 5;          // image
  const int ty   = (bid >> 2) & 7;    // 8-px tile row
  const int tx   = bid & 3;           // 16-px tile col
  const int lane = tid & 63;
  const int wid  = tid >> 6;
  const int ln   = lane & 15;
  const int quad = lane >> 4;

  const f16* __restrict__ wfrag = Wt + (size_t)lane * 8;

  // ---- issue x2 loads first (biggest input, longest latency): 40 x 22 float4 = 880
  f32x4 v2[4];
  int   off2[4];
  bool  ok2[4];
  {
    const float* img = x2 + nb * 65536;
    #pragma unroll
    for (int i = 0; i < 4; ++i) {
      int idx = tid + 256 * i;
      int r  = idx / 22, c4 = idx - r * 22;
      int gy = ty * 32 - 4 + r;
      int gx = tx * 64 - 8 + 4 * c4;
      bool inb = (idx < 880) && ((unsigned)gy < 256u) && ((unsigned)gx < 256u);
      v2[i]  = inb ? *(const f32x4*)(img + gy * 256 + gx) : (f32x4){0.f, 0.f, 0.f, 0.f};
      off2[i] = T2OFF + r * S2 + 4 * c4;
      ok2[i]  = (idx < 880);
    }
  }

  // ---- stage x1 (20 x 11 float4 = 220) and x0 (11 x 6 = 66) ----
  {
    const float* img = x1 + nb * 16384;
    int idx = tid;
    int r  = idx / 11, c4 = idx - r * 11;
    int gy = ty * 16 - 2 + r;
    int gx = tx * 32 - 4 + 4 * c4;
    bool inb = (idx < 220) && ((unsigned)gy < 128u) && ((unsigned)gx < 128u);
    f32x4 t = inb ? *(const f32x4*)(img + gy * 128 + gx) : (f32x4){0.f, 0.f, 0.f, 0.f};
    if (idx < 220) {
      f16x4 h; h[0] = (f16)t[0]; h[1] = (f16)t[1]; h[2] = (f16)t[2]; h[3] = (f16)t[3];
      *(f16x4*)&tiles[T1OFF + r * S1 + 4 * c4] = h;
    }
  }
  {
    const float* img = x0 + nb * 4096;
    int idx = tid;
    int r  = idx / 6, c4 = idx - r * 6;
    int gy = ty * 8 - 1 + r;
    int gx = tx * 16 - 4 + 4 * c4;
    bool inb = (idx < 66) && ((unsigned)gy < 64u) && ((unsigned)gx < 64u);
    f32x4 t = inb ? *(const f32x4*)(img + gy * 64 + gx) : (f32x4){0.f, 0.f, 0.f, 0.f};
    if (idx < 66) {
      f16x4 h; h[0] = (f16)t[0]; h[1] = (f16)t[1]; h[2] = (f16)t[2]; h[3] = (f16)t[3];
      *(f16x4*)&tiles[T0OFF + r * S0 + 4 * c4] = h;
    }
  }

  // x0 scale pixels for the epilogue (exact f32); lane's pixel is (ty*8+wid*2+cc, tx*16+ln)
  float xs[2];
  #pragma unroll
  for (int cc = 0; cc < 2; ++cc)
    xs[cc] = x0[nb * 4096 + (ty * 8 + wid * 2 + cc) * 64 + tx * 16 + ln];

  // ---- x2 -> LDS (the barrier's vmcnt(0) drain means data is here anyway) ----
  #pragma unroll
  for (int i = 0; i < 4; ++i) {
    if (ok2[i]) {
      f16x4 h; h[0] = (f16)v2[i][0]; h[1] = (f16)v2[i][1];
      h[2] = (f16)v2[i][2]; h[3] = (f16)v2[i][3];
      *(f16x4*)&tiles[off2[i]] = h;
    }
  }
  __syncthreads();   // the ONLY barrier: all three tiles ready

  f32x4 acc[2][4];
  #pragma unroll
  for (int c = 0; c < 2; ++c)
    #pragma unroll
    for (int t = 0; t < 4; ++t)
      acc[c][t] = (f32x4){0.f, 0.f, 0.f, 0.f};

  // ---- kstep 0: quads 0,1 -> layer0 ; quads 2,3 -> layer1 ----
  {
    f16x8 bf[4];
    #pragma unroll
    for (int t = 0; t < 4; ++t)
      bf[t] = *(const f16x8*)(wfrag + t * 512);
    #pragma unroll
    for (int cc = 0; cc < 2; ++cc) {
      const int py = wid * 2 + cc;
      f16x8 a;
      if (quad < 2) {
        // layer0: ki = 2*quad + (j>>2), kj = j&3; row = py+ki, col = ln+3+kj
        const int a0 = T0OFF + (py + 2 * quad) * S0 + ln + 3;
        #pragma unroll
        for (int j = 0; j < 4; ++j) a[j]     = tiles[a0 + j];
        #pragma unroll
        for (int j = 0; j < 4; ++j) a[4 + j] = tiles[a0 + S0 + j];
      } else {
        // layer1: ki = quad-2, kj = j; row = 2py+ki, col = 2ln+2+kj
        const int a1 = T1OFF + (2 * py + quad - 2) * S1 + 2 * ln + 2;
        #pragma unroll
        for (int j = 0; j < 8; ++j) a[j] = tiles[a1 + j];
      }
      #pragma unroll
      for (int t = 0; t < 4; ++t)
        acc[cc][t] = __builtin_amdgcn_mfma_f32_16x16x32_f16(bf[t], a, acc[cc][t], 0, 0, 0);
    }
  }
  // ---- kstep 1: all layer1, ki = 2+quad ----
  {
    f16x8 bf[4];
    #pragma unroll
    for (int t = 0; t < 4; ++t)
      bf[t] = *(const f16x8*)(wfrag + (4 + t) * 512);
    #pragma unroll
    for (int cc = 0; cc < 2; ++cc) {
      const int py = wid * 2 + cc;
      const int a1 = T1OFF + (2 * py + 2 + quad) * S1 + 2 * ln + 2;
      f16x8 a;
      #pragma unroll
      for (int j = 0; j < 8; ++j) a[j] = tiles[a1 + j];
      #pragma unroll
      for (int t = 0; t < 4; ++t)
        acc[cc][t] = __builtin_amdgcn_mfma_f32_16x16x32_f16(bf[t], a, acc[cc][t], 0, 0, 0);
    }
  }
  // ---- ksteps 2..7: layer2 ----
  // row = 4py + 2(s-2) + (quad>>1), col = 4ln + 4 + 8(quad&1) + j
  #pragma unroll 3
  for (int s = 2; s < 8; ++s) {
    f16x8 bf[4];
    #pragma unroll
    for (int t = 0; t < 4; ++t)
      bf[t] = *(const f16x8*)(wfrag + (s * 4 + t) * 512);
    #pragma unroll
    for (int cc = 0; cc < 2; ++cc) {
      const int py = wid * 2 + cc;
      const int b2 = T2OFF + (4 * py + 2 * (s - 2) + (quad >> 1)) * S2 + 4 * ln + 4 + 8 * (quad & 1);
      f16x4 lo = *(const f16x4*)&tiles[b2];
      f16x4 hi = *(const f16x4*)&tiles[b2 + 4];
      f16x8 a;
      a[0] = lo[0]; a[1] = lo[1]; a[2] = lo[2]; a[3] = lo[3];
      a[4] = hi[0]; a[5] = hi[1]; a[6] = hi[2]; a[7] = hi[3];
      #pragma unroll
      for (int t = 0; t < 4; ++t)
        acc[cc][t] = __builtin_amdgcn_mfma_f32_16x16x32_f16(bf[t], a, acc[cc][t], 0, 0, 0);
    }
  }

  // ---- epilogue: fully in-register softmax + direct coalesced stores ----
  const int gx8 = (tx * 16 + ln) * 8;
  #pragma unroll
  for (int cc = 0; cc < 2; ++cc) {
    float v[4][4];
    float m = 0.f;                       // logits are post-ReLU, so >= 0
    #pragma unroll
    for (int t = 0; t < 4; ++t)
      #pragma unroll
      for (int r = 0; r < 4; ++r) {
        float x = fmaxf(acc[cc][t][r], 0.f);
        v[t][r] = x;
        m = fmaxf(m, x);
      }
    m = fmaxf(m, __shfl_xor(m, 16));
    m = fmaxf(m, __shfl_xor(m, 32));

    float sden = 0.f;
    #pragma unroll
    for (int t = 0; t < 4; ++t)
      #pragma unroll
      for (int r = 0; r < 4; ++r) {
        float e = exp2f((v[t][r] - m) * LOG2E);
        v[t][r] = e;
        sden += e;
      }
    sden += __shfl_xor(sden, 16);
    sden += __shfl_xor(sden, 32);

    const float sc = xs[cc] / sden;
    const int gy = ty * 8 + wid * 2 + cc;
    // chan = 16t + 4*quad + r -> addr = (gy*8 + 2t + (quad>>1))*512 + gx*8 + 4*(quad&1) + r
    float* op = out + nb * 262144 + (gy * 8 + (quad >> 1)) * 512 + gx8 + 4 * (quad & 1);
    #pragma unroll
    for (int t = 0; t < 4; ++t) {
      f32x4 w;
      w[0] = v[t][0] * sc; w[1] = v[t][1] * sc;
      w[2] = v[t][2] * sc; w[3] = v[t][3] * sc;
      __builtin_nontemporal_store(w, (f32x4*)(op + t * 1024));
    }
  }
}

extern "C" void kernel_launch(void* const* d_in, const int* in_sizes, int n_in,
                              void* d_out, int out_size, void* d_ws, size_t ws_size,
                              hipStream_t stream) {
  const float* x0 = (const float*)d_in[0];
  const float* x1 = (const float*)d_in[1];
  const float* x2 = (const float*)d_in[2];
  const float* W  = (const float*)d_in[3];
  float* outp     = (float*)d_out;
  f16* Wt         = (f16*)d_ws;   // 2048 fragments * 16 B = 32 KB

  prep_wt<<<dim3(8), dim3(256), 0, stream>>>(W, Wt);
  fuse_kernel<<<dim3(2048), dim3(256), 0, stream>>>(x0, x1, x2, Wt, outp);
}